// Round 3
// baseline (1061.357 us; speedup 1.0000x reference)
//
#include <hip/hip_runtime.h>
#include <hip/hip_bf16.h>
#include <stdint.h>

typedef __hip_bfloat16 bf16;
typedef __attribute__((ext_vector_type(8))) short bf16x8;
typedef __attribute__((ext_vector_type(4))) float f32x4;

#define DEV __device__ __forceinline__

static constexpr int Bn = 16, Tn = 512, En = 512, Hn = 8, Ln = 4, Vn = 2048;
static constexpr int HSn = 64, FFn = 2048, Mn = Bn * Tn;  // M = 8192

DEV f32x4 mfma16(bf16x8 a, bf16x8 b, f32x4 c) {
  return __builtin_amdgcn_mfma_f32_16x16x32_bf16(a, b, c, 0, 0, 0);
}
DEV float b2f(bf16 x) { return __bfloat162float(x); }
DEV bf16 f2b(float x) { return __float2bfloat16(x); }

// ------------- transpose+cast: out[z][c][r] = bf16(in[z][r][c]) (fp32 in) -------------
__global__ __launch_bounds__(256) void ktranspose(const float* __restrict__ in,
                                                  bf16* __restrict__ out, int R, int C) {
  __shared__ float tile[32][33];
  int z = blockIdx.z;
  const float* inz = in + (size_t)z * R * C;
  bf16* outz = out + (size_t)z * R * C;
  int c0 = blockIdx.x * 32, r0 = blockIdx.y * 32;
  for (int k = 0; k < 32; k += 8) {
    tile[threadIdx.y + k][threadIdx.x] =
        inz[(size_t)(r0 + threadIdx.y + k) * C + (c0 + threadIdx.x)];
  }
  __syncthreads();
  for (int k = 0; k < 32; k += 8) {
    outz[(size_t)(c0 + threadIdx.y + k) * R + (r0 + threadIdx.x)] =
        f2b(tile[threadIdx.x][threadIdx.y + k]);
  }
}

// ------------- cast fp32 -> bf16 (for rel) -------------
__global__ __launch_bounds__(256) void kcast(const float* __restrict__ in,
                                             bf16* __restrict__ out, int n) {
  int i = blockIdx.x * 256 + threadIdx.x;
  if (i < n) out[i] = f2b(in[i]);
}

// ------------- embedding: x = tok_emb[idx] + pos_emb (fp32 out) -------------
__global__ __launch_bounds__(256) void kembed(const int* __restrict__ idx,
                                              const float* __restrict__ tok,
                                              const float* __restrict__ pos,
                                              float* __restrict__ x) {
  int i = blockIdx.x * 256 + threadIdx.x;  // over M*E
  int e = i & (En - 1);
  int bt = i >> 9;
  int t = bt & (Tn - 1);
  x[i] = tok[(size_t)idx[bt] * En + e] + pos[(size_t)t * En + e];
}

// ------------- LayerNorm: one wave per row of 512, bf16 out -------------
__global__ __launch_bounds__(64) void kln(const float* __restrict__ x,
                                          const float* __restrict__ g,
                                          const float* __restrict__ b,
                                          bf16* __restrict__ out) {
  int row = blockIdx.x;
  int lane = threadIdx.x;
  const float* xr = x + (size_t)row * En;
  float v[8], s = 0.f;
  for (int j = 0; j < 8; j++) { v[j] = xr[lane + j * 64]; s += v[j]; }
  for (int m = 1; m < 64; m <<= 1) s += __shfl_xor(s, m);
  float mean = s * (1.f / En);
  float s2 = 0.f;
  for (int j = 0; j < 8; j++) { float d = v[j] - mean; s2 += d * d; }
  for (int m = 1; m < 64; m <<= 1) s2 += __shfl_xor(s2, m);
  float rstd = rsqrtf(s2 * (1.f / En) + 1e-5f);
  for (int j = 0; j < 8; j++) {
    int e = lane + j * 64;
    out[(size_t)row * En + e] = f2b((v[j] - mean) * rstd * g[e] + b[e]);
  }
}

// ------------- GEMM: C = A[M,K] @ Bt[N,K]^T (+bias/relu) -------------
// MODE: 0 = store bf16 to outh; 1 = fp32 residual += outf; 2 = fp32 store outf.
// 128x128 tile, 4 waves (2x2 of 64x64), BK=32, reg-staged LDS, 16x16x32 bf16 MFMA.
template <int NBIAS, int RELU, int MODE>
__global__ __launch_bounds__(256) void kgemm(const bf16* __restrict__ A,
                                             const bf16* __restrict__ Bt,
                                             const float* __restrict__ bias,
                                             float* __restrict__ outf,
                                             bf16* __restrict__ outh, int Ndim, int K) {
  __shared__ bf16 As[128 * 32];
  __shared__ bf16 Bs[128 * 32];
  int t = threadIdx.x, lane = t & 63, w = t >> 6;
  int lr = lane & 15, lg = lane >> 4;
  int wr = w >> 1, wc = w & 1;
  int br = blockIdx.y * 128, bc = blockIdx.x * 128;
  f32x4 acc[4][4] = {};
  const bf16* Ag = A + (size_t)(br + (t >> 2)) * K + (t & 3) * 8;
  const bf16* Bg = Bt + (size_t)(bc + (t >> 2)) * K + (t & 3) * 8;
  for (int kt = 0; kt < K; kt += 32) {
    *(bf16x8*)&As[t * 8] = *(const bf16x8*)(Ag + kt);
    *(bf16x8*)&As[2048 + t * 8] = *(const bf16x8*)(Ag + (size_t)64 * K + kt);
    *(bf16x8*)&Bs[t * 8] = *(const bf16x8*)(Bg + kt);
    *(bf16x8*)&Bs[2048 + t * 8] = *(const bf16x8*)(Bg + (size_t)64 * K + kt);
    __syncthreads();
    bf16x8 af[4], bf_[4];
    for (int mi = 0; mi < 4; mi++)
      af[mi] = *(const bf16x8*)&As[(wr * 64 + mi * 16 + lr) * 32 + lg * 8];
    for (int ni = 0; ni < 4; ni++)
      bf_[ni] = *(const bf16x8*)&Bs[(wc * 64 + ni * 16 + lr) * 32 + lg * 8];
    for (int mi = 0; mi < 4; mi++)
      for (int ni = 0; ni < 4; ni++)
        acc[mi][ni] = mfma16(af[mi], bf_[ni], acc[mi][ni]);
    __syncthreads();
  }
  for (int mi = 0; mi < 4; mi++)
    for (int ni = 0; ni < 4; ni++)
      for (int r = 0; r < 4; r++) {
        int row = br + wr * 64 + mi * 16 + lg * 4 + r;
        int col = bc + wc * 64 + ni * 16 + lr;
        float val = acc[mi][ni][r];
        if (NBIAS) val += bias[col];
        if (RELU) val = fmaxf(val, 0.f);
        if (MODE == 1) outf[(size_t)row * Ndim + col] += val;
        else if (MODE == 2) outf[(size_t)row * Ndim + col] = val;
        else outh[(size_t)row * Ndim + col] = f2b(val);
      }
}

// ------------- fused causal attention with relative-position scores -------------
// grid: (T/64, B*H); block 256 (4 waves). Wave w owns i-rows [iblk*64+16w, +16).
// q/k/v are raw QKV GEMM outputs; (B,T,E).view(B,H,T,HS) is a flat reinterpret:
// head (b,h) lives at offset (b*H+h)*T*HS, d-contiguous with t-stride HS.
__global__ __launch_bounds__(256) void kattn(const bf16* __restrict__ q,
                                             const bf16* __restrict__ k,
                                             const bf16* __restrict__ v,
                                             const bf16* __restrict__ rel,
                                             bf16* __restrict__ ctx) {
  __shared__ bf16 Ks[64 * 64];        // [j][d]
  __shared__ bf16 Vs[64 * 64];        // transposed: [d][j]
  __shared__ float Prel[4][16 * 80];  // per-wave rel panel
  __shared__ bf16 Ps[4][16 * 64];     // per-wave P (bf16) for PV MFMA
  int iblk = blockIdx.x, bh = blockIdx.y;
  int b = bh >> 3, hh = bh & 7;
  int t = threadIdx.x, lane = t & 63, w = t >> 6;
  int lr = lane & 15, lg = lane >> 4;
  const bf16* qb = q + (size_t)bh * Tn * HSn;
  const bf16* kb = k + (size_t)bh * Tn * HSn;
  const bf16* vb = v + (size_t)bh * Tn * HSn;
  int i0w = iblk * 64 + w * 16;
  bf16x8 aq[2];
  aq[0] = *(const bf16x8*)(qb + (size_t)(i0w + lr) * 64 + lg * 8);
  aq[1] = *(const bf16x8*)(qb + (size_t)(i0w + lr) * 64 + 32 + lg * 8);
  f32x4 o[4] = {};
  float m_run[4], l_run[4];
  for (int r = 0; r < 4; r++) { m_run[r] = -3e38f; l_run[r] = 0.f; }
  float* prw = &Prel[w][0];
  bf16* psw = &Ps[w][0];

  for (int jb = 0; jb <= iblk * 64; jb += 64) {
    __syncthreads();  // protect Ks/Vs from previous iteration's readers
    {  // stage K tile [64][64]
      const bf16* src = kb + (size_t)(jb + (t >> 3)) * 64 + (t & 7) * 8;
      *(bf16x8*)&Ks[t * 8] = *(const bf16x8*)src;
      *(bf16x8*)&Ks[2048 + t * 8] = *(const bf16x8*)(src + 32 * 64);
    }
    {  // stage V transposed: Vs[d][j]
      int jv = t >> 2;
      for (int p = 0; p < 2; p++) {
        int d0 = (t & 3) * 8 + p * 32;
        bf16x8 vv = *(const bf16x8*)(vb + (size_t)(jb + jv) * 64 + d0);
        const short* vsp = (const short*)&vv;
        for (int u = 0; u < 8; u++) ((short*)Vs)[(d0 + u) * 64 + jv] = vsp[u];
      }
    }
    __syncthreads();
    // QK^T: S (16 x 64) per wave
    f32x4 sqk[4] = {};
    for (int nj = 0; nj < 4; nj++) {
      bf16x8 b0 = *(const bf16x8*)&Ks[(nj * 16 + lr) * 64 + lg * 8];
      sqk[nj] = mfma16(aq[0], b0, sqk[nj]);
      bf16x8 b1 = *(const bf16x8*)&Ks[(nj * 16 + lr) * 64 + 32 + lg * 8];
      sqk[nj] = mfma16(aq[1], b1, sqk[nj]);
    }
    // rel panel: Prel (16 x 80) = Q @ rel[base..base+79]^T
    int base = i0w - jb + 448;
    f32x4 sr[5] = {};
    for (int nm = 0; nm < 5; nm++) {
      int mrow = base + nm * 16 + lr;
      if (mrow > 1022) mrow = 1022;  // mm=79 column is never gathered
      const bf16* rp = rel + (size_t)mrow * 64 + lg * 8;
      bf16x8 r0 = *(const bf16x8*)rp;
      sr[nm] = mfma16(aq[0], r0, sr[nm]);
      bf16x8 r1 = *(const bf16x8*)(rp + 32);
      sr[nm] = mfma16(aq[1], r1, sr[nm]);
    }
    for (int nm = 0; nm < 5; nm++)
      for (int r = 0; r < 4; r++)
        prw[(lg * 4 + r) * 80 + nm * 16 + lr] = sr[nm][r];
    __syncthreads();
    // assemble S = 0.125*QK + rel-gather, causal mask, online softmax
    float sv[4][4], mx[4];
    for (int r = 0; r < 4; r++) {
      int ii = lg * 4 + r;
      float mxr = -3e38f;
      for (int nj = 0; nj < 4; nj++) {
        int jj = nj * 16 + lr;
        float val = sqk[nj][r] * 0.125f + prw[ii * 80 + (ii - jj + 63)];
        if (jb + jj > i0w + ii) val = -3e38f;  // causal
        sv[nj][r] = val;
        mxr = fmaxf(mxr, val);
      }
      for (int msk = 1; msk < 16; msk <<= 1) mxr = fmaxf(mxr, __shfl_xor(mxr, msk));
      mx[r] = mxr;
    }
    for (int r = 0; r < 4; r++) {
      float mnew = fmaxf(m_run[r], mx[r]);
      float corr = __expf(m_run[r] - mnew);
      float rs = 0.f;
      for (int nj = 0; nj < 4; nj++) {
        float p = __expf(sv[nj][r] - mnew);
        rs += p;
        psw[(lg * 4 + r) * 64 + nj * 16 + lr] = f2b(p);
      }
      for (int msk = 1; msk < 16; msk <<= 1) rs += __shfl_xor(rs, msk);
      l_run[r] = l_run[r] * corr + rs;
      m_run[r] = mnew;
      for (int nd = 0; nd < 4; nd++) o[nd][r] *= corr;
    }
    __syncthreads();
    // PV: O += P @ V
    bf16x8 ap[2];
    ap[0] = *(const bf16x8*)&psw[lr * 64 + lg * 8];
    ap[1] = *(const bf16x8*)&psw[lr * 64 + 32 + lg * 8];
    for (int nd = 0; nd < 4; nd++) {
      bf16x8 b0 = *(const bf16x8*)&((short*)Vs)[(nd * 16 + lr) * 64 + lg * 8];
      o[nd] = mfma16(ap[0], b0, o[nd]);
      bf16x8 b1 = *(const bf16x8*)&((short*)Vs)[(nd * 16 + lr) * 64 + 32 + lg * 8];
      o[nd] = mfma16(ap[1], b1, o[nd]);
    }
  }
  // ctx[b, t=i, h*HS+d]  (swapaxes(1,2).reshape)
  for (int nd = 0; nd < 4; nd++)
    for (int r = 0; r < 4; r++) {
      int row = i0w + lg * 4 + r;
      ctx[((size_t)b * Tn + row) * En + hh * 64 + nd * 16 + lr] =
          f2b(o[nd][r] / l_run[r]);
    }
}

// ------------- launch -------------
extern "C" void kernel_launch(void* const* d_in, const int* in_sizes, int n_in,
                              void* d_out, int out_size, void* d_ws, size_t ws_size,
                              hipStream_t stream) {
  (void)in_sizes; (void)n_in; (void)out_size; (void)ws_size;
  const int* idx = (const int*)d_in[0];
  const float* tok = (const float*)d_in[1];
  const float* pos = (const float*)d_in[2];
  const float* Wq = (const float*)d_in[3];
  const float* Wk = (const float*)d_in[4];
  const float* Wv = (const float*)d_in[5];
  const float* rel = (const float*)d_in[6];
  const float* Wo = (const float*)d_in[7];
  const float* bo = (const float*)d_in[8];
  const float* ln1_g = (const float*)d_in[9];
  const float* ln1_b = (const float*)d_in[10];
  const float* W1 = (const float*)d_in[11];
  const float* b1 = (const float*)d_in[12];
  const float* W2 = (const float*)d_in[13];
  const float* b2 = (const float*)d_in[14];
  const float* ln2_g = (const float*)d_in[15];
  const float* ln2_b = (const float*)d_in[16];
  const float* lnf_g = (const float*)d_in[17];
  const float* lnf_b = (const float*)d_in[18];
  const float* Wlm = (const float*)d_in[19];
  const float* blm = (const float*)d_in[20];

  char* ws = (char*)d_ws;
  // workspace layout (bytes), total ~82.5 MB
  float* x = (float*)(ws + 0);                       // 16,777,216 fp32 residual
  bf16* h = (bf16*)(ws + 16777216);                  //  8,388,608 LN out
  bf16* qb = (bf16*)(ws + 25165824);                 // q|k|v 24 MB
  bf16* kb = qb + (size_t)Mn * En;
  bf16* vb = kb + (size_t)Mn * En;
  bf16* ctx = (bf16*)(ws + 50331648);                //  8,388,608
  bf16* ffn1 = qb;                                   // 32 MB alias over q|k|v|ctx
  bf16* wqT = (bf16*)(ws + 58720256);                // transposed weights 27.3 MB
  bf16* wkT = wqT + (size_t)Ln * En * En;
  bf16* wvT = wkT + (size_t)Ln * En * En;
  bf16* woT = wvT + (size_t)Ln * En * En;
  bf16* w1T = woT + (size_t)Ln * En * En;
  bf16* w2T = w1T + (size_t)Ln * En * FFn;
  bf16* wlmT = w2T + (size_t)Ln * FFn * En;
  bf16* relc = wlmT + (size_t)En * Vn;               // 523,776 B
  float* outf = (float*)d_out;

  dim3 tb(32, 8);
  // weight transposes+cast: [K][N] fp32 -> [N][K] bf16
  ktranspose<<<dim3(En / 32, En / 32, Ln), tb, 0, stream>>>(Wq, wqT, En, En);
  ktranspose<<<dim3(En / 32, En / 32, Ln), tb, 0, stream>>>(Wk, wkT, En, En);
  ktranspose<<<dim3(En / 32, En / 32, Ln), tb, 0, stream>>>(Wv, wvT, En, En);
  ktranspose<<<dim3(En / 32, En / 32, Ln), tb, 0, stream>>>(Wo, woT, En, En);
  ktranspose<<<dim3(FFn / 32, En / 32, Ln), tb, 0, stream>>>(W1, w1T, En, FFn);
  ktranspose<<<dim3(En / 32, FFn / 32, Ln), tb, 0, stream>>>(W2, w2T, FFn, En);
  ktranspose<<<dim3(Vn / 32, En / 32, 1), tb, 0, stream>>>(Wlm, wlmT, En, Vn);
  kcast<<<(Ln * (2 * Tn - 1) * HSn + 255) / 256, 256, 0, stream>>>(
      rel, relc, Ln * (2 * Tn - 1) * HSn);

  kembed<<<(Mn * En) / 256, 256, 0, stream>>>(idx, tok, pos, x);

  for (int l = 0; l < Ln; l++) {
    kln<<<Mn, 64, 0, stream>>>(x, ln1_g + (size_t)l * En, ln1_b + (size_t)l * En, h);
    kgemm<0, 0, 0><<<dim3(4, 64), 256, 0, stream>>>(
        h, wqT + (size_t)l * En * En, nullptr, nullptr, qb, En, En);
    kgemm<0, 0, 0><<<dim3(4, 64), 256, 0, stream>>>(
        h, wkT + (size_t)l * En * En, nullptr, nullptr, kb, En, En);
    kgemm<0, 0, 0><<<dim3(4, 64), 256, 0, stream>>>(
        h, wvT + (size_t)l * En * En, nullptr, nullptr, vb, En, En);
    kattn<<<dim3(Tn / 64, Bn * Hn), 256, 0, stream>>>(
        qb, kb, vb, relc + (size_t)l * (2 * Tn - 1) * HSn, ctx);
    kgemm<1, 0, 1><<<dim3(4, 64), 256, 0, stream>>>(
        ctx, woT + (size_t)l * En * En, bo + (size_t)l * En, x, nullptr, En, En);
    kln<<<Mn, 64, 0, stream>>>(x, ln2_g + (size_t)l * En, ln2_b + (size_t)l * En, h);
    kgemm<1, 1, 0><<<dim3(16, 64), 256, 0, stream>>>(
        h, w1T + (size_t)l * En * FFn, b1 + (size_t)l * FFn, nullptr, ffn1, FFn, En);
    kgemm<1, 0, 1><<<dim3(4, 64), 256, 0, stream>>>(
        ffn1, w2T + (size_t)l * FFn * En, b2 + (size_t)l * En, x, nullptr, En, FFn);
  }
  kln<<<Mn, 64, 0, stream>>>(x, lnf_g, lnf_b, h);
  kgemm<1, 0, 2><<<dim3(16, 64), 256, 0, stream>>>(
      h, wlmT, blm, outf, nullptr, Vn, En);
}

// Round 4
// 839.995 us; speedup vs baseline: 1.2635x; 1.2635x over previous
//
#include <hip/hip_runtime.h>
#include <hip/hip_bf16.h>
#include <stdint.h>

typedef __hip_bfloat16 bf16;
typedef __attribute__((ext_vector_type(8))) short bf16x8;
typedef __attribute__((ext_vector_type(8))) short short8;
typedef __attribute__((ext_vector_type(4))) float f32x4;

#define DEV __device__ __forceinline__

static constexpr int Bn = 16, Tn = 512, En = 512, Hn = 8, Ln = 4, Vn = 2048;
static constexpr int HSn = 64, FFn = 2048, Mn = Bn * Tn;  // M = 8192
static constexpr int SQ = 1536;                           // fused qkv row stride

DEV f32x4 mfma16(bf16x8 a, bf16x8 b, f32x4 c) {
  return __builtin_amdgcn_mfma_f32_16x16x32_bf16(a, b, c, 0, 0, 0);
}
DEV float b2f(bf16 x) { return __bfloat162float(x); }
DEV bf16 f2b(float x) { return __float2bfloat16(x); }

// async global->LDS, 16B per lane; LDS dest = base + lane*16 (wave-uniform base).
DEV void gload16(const void* g, void* l) {
  __builtin_amdgcn_global_load_lds(
      (const __attribute__((address_space(1))) void*)(uintptr_t)g,
      (__attribute__((address_space(3))) void*)(uint32_t)(uintptr_t)l, 16, 0, 0);
}

// ------------- transpose+cast: out[z][c][r] = bf16(in[z][r][c]) -------------
__global__ __launch_bounds__(256) void ktranspose(const float* __restrict__ in,
                                                  bf16* __restrict__ out, int R, int C,
                                                  long in_zs, long out_zs) {
  __shared__ float tile[32][33];
  int z = blockIdx.z;
  const float* inz = in + (size_t)z * in_zs;
  bf16* outz = out + (size_t)z * out_zs;
  int c0 = blockIdx.x * 32, r0 = blockIdx.y * 32;
  for (int k = 0; k < 32; k += 8)
    tile[threadIdx.y + k][threadIdx.x] =
        inz[(size_t)(r0 + threadIdx.y + k) * C + (c0 + threadIdx.x)];
  __syncthreads();
  for (int k = 0; k < 32; k += 8)
    outz[(size_t)(c0 + threadIdx.y + k) * R + (r0 + threadIdx.x)] =
        f2b(tile[threadIdx.x][threadIdx.y + k]);
}

// ------------- cast fp32 -> bf16 (rel) -------------
__global__ __launch_bounds__(256) void kcast(const float* __restrict__ in,
                                             bf16* __restrict__ out, int n) {
  int i = blockIdx.x * 256 + threadIdx.x;
  if (i < n) out[i] = f2b(in[i]);
}

// ------------- embedding (f32x4) -------------
__global__ __launch_bounds__(256) void kembed(const int* __restrict__ idx,
                                              const float* __restrict__ tok,
                                              const float* __restrict__ pos,
                                              float* __restrict__ x) {
  int i = blockIdx.x * 256 + threadIdx.x;  // over M*E/4
  int e4 = (i & 127) * 4;
  int bt = i >> 7;
  int t = bt & (Tn - 1);
  f32x4 tv = *(const f32x4*)(tok + (size_t)idx[bt] * En + e4);
  f32x4 pv = *(const f32x4*)(pos + (size_t)t * En + e4);
  *(f32x4*)(x + (size_t)bt * En + e4) = tv + pv;
}

// ------------- LayerNorm: 4 rows/block, wave per row -------------
__global__ __launch_bounds__(256) void kln(const float* __restrict__ x,
                                           const float* __restrict__ g,
                                           const float* __restrict__ b,
                                           bf16* __restrict__ out) {
  int row = blockIdx.x * 4 + (threadIdx.x >> 6);
  int lane = threadIdx.x & 63;
  const float* xr = x + (size_t)row * En + lane * 8;
  f32x4 a0 = *(const f32x4*)xr;
  f32x4 a1 = *(const f32x4*)(xr + 4);
  float s = a0[0] + a0[1] + a0[2] + a0[3] + a1[0] + a1[1] + a1[2] + a1[3];
  for (int m = 1; m < 64; m <<= 1) s += __shfl_xor(s, m);
  float mean = s * (1.f / En);
  float s2 = 0.f;
  for (int j = 0; j < 4; j++) { float d0 = a0[j] - mean, d1 = a1[j] - mean; s2 += d0 * d0 + d1 * d1; }
  for (int m = 1; m < 64; m <<= 1) s2 += __shfl_xor(s2, m);
  float rstd = rsqrtf(s2 * (1.f / En) + 1e-5f);
  f32x4 g0 = *(const f32x4*)(g + lane * 8), g1 = *(const f32x4*)(g + lane * 8 + 4);
  f32x4 b0 = *(const f32x4*)(b + lane * 8), b1 = *(const f32x4*)(b + lane * 8 + 4);
  short8 ov;
  for (int j = 0; j < 4; j++) {
    bf16 h0 = f2b((a0[j] - mean) * rstd * g0[j] + b0[j]);
    bf16 h1 = f2b((a1[j] - mean) * rstd * g1[j] + b1[j]);
    ov[j] = reinterpret_cast<short&>(h0);
    ov[j + 4] = reinterpret_cast<short&>(h1);
  }
  *(short8*)(out + (size_t)row * En + lane * 8) = ov;
}

// ------------- GEMM: C = A[M,K] @ Bt[N,K]^T, 128x128 tile, BK=64, gload_lds ------
// MODE: 0 bf16 store; 1 fp32 resid +=; 2 fp32 store.
template <int NBIAS, int RELU, int MODE>
__global__ __launch_bounds__(256) void kgemm(const bf16* __restrict__ A,
                                             const bf16* __restrict__ Bt,
                                             const float* __restrict__ bias,
                                             float* __restrict__ outf,
                                             bf16* __restrict__ outh, int Ndim, int K) {
  __shared__ bf16 As[128 * 64];
  __shared__ bf16 Bs[128 * 64];
  int t = threadIdx.x, lane = t & 63, w = t >> 6;
  int lr = lane & 15, lg = lane >> 4;
  int sx = lr & 7;
  int wr = w >> 1, wc = w & 1;
  int br = blockIdx.y * 128, bc = blockIdx.x * 128;
  f32x4 acc[4][4] = {};
  int rl = lane >> 3, cb = (lane & 7) ^ rl;  // source col-block pre-swizzle
  const bf16* Abase = A + (size_t)(br + w * 32 + rl) * K + cb * 8;
  const bf16* Bbase = Bt + (size_t)(bc + w * 32 + rl) * K + cb * 8;
  for (int kt = 0; kt < K; kt += 64) {
    __syncthreads();
    for (int c = 0; c < 4; c++) {
      gload16(Abase + (size_t)(c * 8) * K + kt, &As[(w * 32 + c * 8) * 64]);
      gload16(Bbase + (size_t)(c * 8) * K + kt, &Bs[(w * 32 + c * 8) * 64]);
    }
    __syncthreads();
    for (int kk = 0; kk < 2; kk++) {
      int gb = (kk * 4 + lg) ^ sx;
      bf16x8 af[4], bfr[4];
      for (int mi = 0; mi < 4; mi++)
        af[mi] = *(const bf16x8*)&As[(wr * 64 + mi * 16 + lr) * 64 + gb * 8];
      for (int ni = 0; ni < 4; ni++)
        bfr[ni] = *(const bf16x8*)&Bs[(wc * 64 + ni * 16 + lr) * 64 + gb * 8];
      for (int mi = 0; mi < 4; mi++)
        for (int ni = 0; ni < 4; ni++)
          acc[mi][ni] = mfma16(af[mi], bfr[ni], acc[mi][ni]);
    }
  }
  for (int mi = 0; mi < 4; mi++)
    for (int ni = 0; ni < 4; ni++)
      for (int r = 0; r < 4; r++) {
        int row = br + wr * 64 + mi * 16 + lg * 4 + r;
        int col = bc + wc * 64 + ni * 16 + lr;
        float val = acc[mi][ni][r];
        if (NBIAS) val += bias[col];
        if (RELU) val = fmaxf(val, 0.f);
        if (MODE == 1) outf[(size_t)row * Ndim + col] += val;
        else if (MODE == 2) outf[(size_t)row * Ndim + col] = val;
        else outh[(size_t)row * Ndim + col] = f2b(val);
      }
}

// ------------- fused causal attention + rel-position -------------
// Fused qkv [M][1536]; view(B,H,T,HS) semantics: x[b,h,t2,d] =
//   qkv[(b*512 + h*64 + (t2>>3))*1536 + koffs + (t2&7)*64 + d], koffs in {0,512,1024}.
// grid (4 pairs, 128 bh); block = 4 waves; block handles i-blocks (p, 7-p) -> 9 iters.
__global__ __launch_bounds__(256) void kattn(const bf16* __restrict__ qkv,
                                             const bf16* __restrict__ rel,
                                             bf16* __restrict__ ctx) {
  __shared__ bf16 Ks[64 * 64];        // [j][d], col-block XOR (j&7)
  __shared__ bf16 Vs[64 * 64];        // [d][j], col-block XOR (d&7)
  __shared__ float Prel[4][16 * 81];  // per-wave rel panel, stride 81
  __shared__ bf16 Ps[4][16 * 64];     // per-wave P, col-block XOR (i&7)
  int pairp = blockIdx.x, bh = blockIdx.y;
  int b = bh >> 3, hh = bh & 7;
  int t = threadIdx.x, lane = t & 63, w = t >> 6;
  int lr = lane & 15, lg = lane >> 4;
  int sx = lr & 7;
  int rl8 = lane >> 3, cbk = (lane & 7) ^ rl8;
  const size_t headrow = (size_t)(b * Tn + hh * 64);
  float* prw = &Prel[w][0];
  bf16* psw = &Ps[w][0];

  for (int ph = 0; ph < 2; ph++) {
    int iblk = ph ? (7 - pairp) : pairp;
    int i0w = iblk * 64 + w * 16;
    bf16x8 aq[2];
    {
      int t2 = i0w + lr;
      const bf16* qp = qkv + (headrow + (t2 >> 3)) * SQ + (t2 & 7) * 64;
      aq[0] = *(const bf16x8*)(qp + lg * 8);
      aq[1] = *(const bf16x8*)(qp + 32 + lg * 8);
    }
    f32x4 o[4] = {};
    float m_run[4], l_run[4];
    for (int r = 0; r < 4; r++) { m_run[r] = -3e38f; l_run[r] = 0.f; }

    for (int jb = 0; jb <= iblk * 64; jb += 64) {
      bool diag = (jb == iblk * 64);
      __syncthreads();  // previous-iter readers done
      // K stage via gload_lds, source pre-swizzled
      for (int c = 0; c < 2; c++) {
        int row = w * 16 + c * 8 + rl8;
        const bf16* src = qkv + (headrow + ((jb + row) >> 3)) * SQ +
                          (row & 7) * 64 + 512 + cbk * 8;
        gload16(src, &Ks[(w * 16 + c * 8) * 64]);
      }
      // V stage: register transpose, swizzled scalar stores
      {
        int jv = t >> 2;
        const bf16* vrow = qkv + (headrow + ((jb + jv) >> 3)) * SQ + (jv & 7) * 64 + 1024;
        for (int p32 = 0; p32 < 2; p32++) {
          int d0 = (t & 3) * 8 + p32 * 32;
          bf16x8 vv = *(const bf16x8*)(vrow + d0);
          const short* vsp = (const short*)&vv;
          for (int u = 0; u < 8; u++) {
            int d = d0 + u;
            ((short*)Vs)[d * 64 + (((jv >> 3) ^ (d & 7)) * 8) + (jv & 7)] = vsp[u];
          }
        }
      }
      __syncthreads();
      int njmax = diag ? w : 3;
      int nmmin = diag ? 3 - w : 0;
      // QK^T
      f32x4 sqk[4] = {};
      for (int nj = 0; nj <= njmax; nj++) {
        int row = nj * 16 + lr;
        bf16x8 kb0 = *(const bf16x8*)&Ks[row * 64 + ((lg ^ sx) * 8)];
        bf16x8 kb1 = *(const bf16x8*)&Ks[row * 64 + (((4 + lg) ^ sx) * 8)];
        sqk[nj] = mfma16(aq[0], kb0, sqk[nj]);
        sqk[nj] = mfma16(aq[1], kb1, sqk[nj]);
      }
      // rel panel (per-wave, no barrier needed)
      int base = i0w - jb + 448;
      for (int nm = nmmin; nm < 5; nm++) {
        int mrow = base + nm * 16 + lr;
        if (mrow > 1022) mrow = 1022;
        const bf16* rp = rel + (size_t)mrow * 64;
        f32x4 sr = {};
        sr = mfma16(aq[0], *(const bf16x8*)(rp + lg * 8), sr);
        sr = mfma16(aq[1], *(const bf16x8*)(rp + 32 + lg * 8), sr);
        for (int r = 0; r < 4; r++)
          prw[(lg * 4 + r) * 81 + nm * 16 + lr] = sr[r];
      }
      // softmax assemble (reads own wave's Prel)
      float sv[4][4];
      for (int nj = 0; nj < 4; nj++)
        for (int r = 0; r < 4; r++) sv[nj][r] = -3e38f;
      float mx[4];
      for (int r = 0; r < 4; r++) {
        int ii = lg * 4 + r;
        float mxr = -3e38f;
        for (int nj = 0; nj <= njmax; nj++) {
          int jj = nj * 16 + lr;
          float val = sqk[nj][r] * 0.125f + prw[ii * 81 + (ii - jj + 63)];
          if (jb + jj > i0w + ii) val = -3e38f;
          sv[nj][r] = val;
          mxr = fmaxf(mxr, val);
        }
        for (int msk = 1; msk < 16; msk <<= 1) mxr = fmaxf(mxr, __shfl_xor(mxr, msk));
        mx[r] = mxr;
      }
      for (int r = 0; r < 4; r++) {
        int ii = lg * 4 + r;
        float mnew = fmaxf(m_run[r], mx[r]);
        float corr = __expf(m_run[r] - mnew);
        float rs = 0.f;
        for (int nj = 0; nj < 4; nj++) {
          float p = __expf(sv[nj][r] - mnew);
          rs += p;
          psw[ii * 64 + (((nj * 2 + (lr >> 3)) ^ (ii & 7)) * 8) + (lr & 7)] = f2b(p);
        }
        for (int msk = 1; msk < 16; msk <<= 1) rs += __shfl_xor(rs, msk);
        l_run[r] = l_run[r] * corr + rs;
        m_run[r] = mnew;
        for (int nd = 0; nd < 4; nd++) o[nd][r] *= corr;
      }
      // PV (own wave's Ps; Vs after barrier)
      bf16x8 ap0 = *(const bf16x8*)&psw[lr * 64 + ((lg ^ sx) * 8)];
      bf16x8 ap1 = *(const bf16x8*)&psw[lr * 64 + (((4 + lg) ^ sx) * 8)];
      for (int nd = 0; nd < 4; nd++) {
        int d = nd * 16 + lr;
        bf16x8 vb0 = *(const bf16x8*)&Vs[d * 64 + ((lg ^ sx) * 8)];
        bf16x8 vb1 = *(const bf16x8*)&Vs[d * 64 + (((4 + lg) ^ sx) * 8)];
        o[nd] = mfma16(ap0, vb0, o[nd]);
        o[nd] = mfma16(ap1, vb1, o[nd]);
      }
    }  // jb
    for (int nd = 0; nd < 4; nd++)
      for (int r = 0; r < 4; r++) {
        int row = i0w + lg * 4 + r;
        ctx[((size_t)b * Tn + row) * En + hh * 64 + nd * 16 + lr] =
            f2b(o[nd][r] / l_run[r]);
      }
  }  // ph
}

// ------------- launch -------------
extern "C" void kernel_launch(void* const* d_in, const int* in_sizes, int n_in,
                              void* d_out, int out_size, void* d_ws, size_t ws_size,
                              hipStream_t stream) {
  (void)in_sizes; (void)n_in; (void)out_size; (void)ws_size;
  const int* idx = (const int*)d_in[0];
  const float* tok = (const float*)d_in[1];
  const float* pos = (const float*)d_in[2];
  const float* Wq = (const float*)d_in[3];
  const float* Wk = (const float*)d_in[4];
  const float* Wv = (const float*)d_in[5];
  const float* rel = (const float*)d_in[6];
  const float* Wo = (const float*)d_in[7];
  const float* bo = (const float*)d_in[8];
  const float* ln1_g = (const float*)d_in[9];
  const float* ln1_b = (const float*)d_in[10];
  const float* W1 = (const float*)d_in[11];
  const float* b1 = (const float*)d_in[12];
  const float* W2 = (const float*)d_in[13];
  const float* b2 = (const float*)d_in[14];
  const float* ln2_g = (const float*)d_in[15];
  const float* ln2_b = (const float*)d_in[16];
  const float* lnf_g = (const float*)d_in[17];
  const float* lnf_b = (const float*)d_in[18];
  const float* Wlm = (const float*)d_in[19];
  const float* blm = (const float*)d_in[20];

  char* ws = (char*)d_ws;
  float* x = (float*)(ws + 0);               // 16 MB fp32 residual
  bf16* h = (bf16*)(ws + 16777216);          // 8 MB LN out
  bf16* qkv = (bf16*)(ws + 25165824);        // 24 MB fused q|k|v [M][1536]
  bf16* ctx = (bf16*)(ws + 50331648);        // 8 MB
  bf16* ffn1 = qkv;                          // 32 MB alias over qkv+ctx
  bf16* wqkvT = (bf16*)(ws + 58720256);      // [L][1536][512] 6 MB
  bf16* woT = wqkvT + (size_t)Ln * SQ * En;
  bf16* w1T = woT + (size_t)Ln * En * En;
  bf16* w2T = w1T + (size_t)Ln * En * FFn;
  bf16* wlmT = w2T + (size_t)Ln * FFn * En;
  bf16* relc = wlmT + (size_t)En * Vn;
  float* outf = (float*)d_out;

  dim3 tb(32, 8);
  ktranspose<<<dim3(16, 16, Ln), tb, 0, stream>>>(Wq, wqkvT, En, En, (long)En * En, (long)SQ * En);
  ktranspose<<<dim3(16, 16, Ln), tb, 0, stream>>>(Wk, wqkvT + 512 * 512, En, En, (long)En * En, (long)SQ * En);
  ktranspose<<<dim3(16, 16, Ln), tb, 0, stream>>>(Wv, wqkvT + 2 * 512 * 512, En, En, (long)En * En, (long)SQ * En);
  ktranspose<<<dim3(16, 16, Ln), tb, 0, stream>>>(Wo, woT, En, En, (long)En * En, (long)En * En);
  ktranspose<<<dim3(64, 16, Ln), tb, 0, stream>>>(W1, w1T, En, FFn, (long)En * FFn, (long)En * FFn);
  ktranspose<<<dim3(16, 64, Ln), tb, 0, stream>>>(W2, w2T, FFn, En, (long)FFn * En, (long)FFn * En);
  ktranspose<<<dim3(64, 16, 1), tb, 0, stream>>>(Wlm, wlmT, En, Vn, 0, 0);
  kcast<<<(Ln * (2 * Tn - 1) * HSn + 255) / 256, 256, 0, stream>>>(
      rel, relc, Ln * (2 * Tn - 1) * HSn);

  kembed<<<(Mn * En / 4) / 256, 256, 0, stream>>>(idx, tok, pos, x);

  for (int l = 0; l < Ln; l++) {
    kln<<<Mn / 4, 256, 0, stream>>>(x, ln1_g + (size_t)l * En, ln1_b + (size_t)l * En, h);
    kgemm<0, 0, 0><<<dim3(12, 64), 256, 0, stream>>>(
        h, wqkvT + (size_t)l * SQ * En, nullptr, nullptr, qkv, SQ, En);
    kattn<<<dim3(4, 128), 256, 0, stream>>>(
        qkv, relc + (size_t)l * (2 * Tn - 1) * HSn, ctx);
    kgemm<1, 0, 1><<<dim3(4, 64), 256, 0, stream>>>(
        ctx, woT + (size_t)l * En * En, bo + (size_t)l * En, x, nullptr, En, En);
    kln<<<Mn / 4, 256, 0, stream>>>(x, ln2_g + (size_t)l * En, ln2_b + (size_t)l * En, h);
    kgemm<1, 1, 0><<<dim3(16, 64), 256, 0, stream>>>(
        h, w1T + (size_t)l * En * FFn, b1 + (size_t)l * FFn, nullptr, ffn1, FFn, En);
    kgemm<1, 0, 1><<<dim3(4, 64), 256, 0, stream>>>(
        ffn1, w2T + (size_t)l * FFn * En, b2 + (size_t)l * En, x, nullptr, En, FFn);
  }
  kln<<<Mn / 4, 256, 0, stream>>>(x, lnf_g, lnf_b, h);
  kgemm<1, 0, 2><<<dim3(16, 64), 256, 0, stream>>>(
      h, wlmT, blm, outf, nullptr, Vn, En);
}